// Round 1
// baseline (335.623 us; speedup 1.0000x reference)
//
#include <hip/hip_runtime.h>

// ---------------------------------------------------------------------------
// MambaBlock fused pipeline, MI355X (gfx950)
// B=2, L=1024, D_MODEL=1024, D_INNER=2048, D_STATE=16, D_CONV=4, DT_RANK=64
//
// Pipeline:
//   1) bf16 casts/transposes of x, W_in, W_x, W_dt, W_out (weights -> B^T layout)
//   2) xz = x @ W_in                 (bf16 MFMA, fp32 acc)  17.2 GF
//   3) u  = silu(causal_conv(xz[:,:,:2048]))                (fp32, writes fp32+bf16)
//   4) x_dbl = u @ W_x               (bf16 MFMA, N=96 guarded)
//   5) delta = softplus(dt @ W_dt + b_dt)   (bf16 MFMA + fp32 epilogue)
//   6) selective scan: 3-pass chunked (local scan / carry stitch / replay+epilogue)
//      thread-per-(b,d), h[16] in VGPRs, B/C via wave-uniform scalar loads
//   7) out = y @ W_out               (bf16 MFMA, fp32 out)
// ---------------------------------------------------------------------------

typedef unsigned short u16;
typedef unsigned int   u32;

#define B_SZ 2
#define L_SZ 1024
#define DM   1024
#define DI   2048
#define DS   16
#define DTR  64
#define NXD  96      /* DTR + 2*DS */
#define NCHUNK 16
#define CL   64      /* chunk length: NCHUNK*CL = L */

typedef __bf16 bf16x8 __attribute__((ext_vector_type(8)));
typedef float  f32x4  __attribute__((ext_vector_type(4)));

__device__ __forceinline__ u16 f2bf(float f) {
    u32 x = __float_as_uint(f);
    x += 0x7fffu + ((x >> 16) & 1u);   // round-to-nearest-even
    return (u16)(x >> 16);
}

// ---------------------------------------------------------------------------
// Generic bf16 GEMM: C[M,N] = A[M,K] * BT[N,K]^T, fp32 accumulate/output.
// Tile 128(M) x 64(N) x 32(K); 256 threads = 4 waves; wave computes 32x64.
// Requires: M % 128 == 0, K % 32 == 0. N guarded (for N=96).
// ---------------------------------------------------------------------------
__global__ __launch_bounds__(256) void gemm_bt_bf16(
    const u16* __restrict__ A, const u16* __restrict__ BT,
    float* __restrict__ C, int M, int N, int K)
{
    constexpr int LDT = 40;                 // 32 + 8 pad (shorts) -> 2-way max
    __shared__ u16 As[128 * LDT];
    __shared__ u16 Bs[64 * LDT];

    const int tid  = threadIdx.x;
    const int wave = tid >> 6;
    const int lane = tid & 63;
    const int q    = lane >> 4;             // k-quad
    const int r16  = lane & 15;
    const int m0   = blockIdx.y * 128;
    const int n0   = blockIdx.x * 64;
    const int sr   = tid >> 2;              // staging row 0..63
    const int ss   = (tid & 3) * 8;         // staging k-segment (shorts)

    f32x4 acc[2][4];
#pragma unroll
    for (int s = 0; s < 2; ++s)
#pragma unroll
        for (int j = 0; j < 4; ++j) acc[s][j] = (f32x4){0.f, 0.f, 0.f, 0.f};

    const int  bcol   = n0 + sr;
    const bool bvalid = bcol < N;

    for (int k0 = 0; k0 < K; k0 += 32) {
        __syncthreads();
        uint4 a0 = *(const uint4*)(A + (size_t)(m0 + sr)      * K + k0 + ss);
        uint4 a1 = *(const uint4*)(A + (size_t)(m0 + 64 + sr) * K + k0 + ss);
        uint4 bv = make_uint4(0u, 0u, 0u, 0u);
        if (bvalid) bv = *(const uint4*)(BT + (size_t)bcol * K + k0 + ss);
        *(uint4*)(As + sr * LDT + ss)        = a0;
        *(uint4*)(As + (64 + sr) * LDT + ss) = a1;
        *(uint4*)(Bs + sr * LDT + ss)        = bv;
        __syncthreads();

        bf16x8 af[2], bfr[4];
#pragma unroll
        for (int s = 0; s < 2; ++s)
            af[s] = *(const bf16x8*)(As + (wave * 32 + s * 16 + r16) * LDT + q * 8);
#pragma unroll
        for (int j = 0; j < 4; ++j)
            bfr[j] = *(const bf16x8*)(Bs + (j * 16 + r16) * LDT + q * 8);
#pragma unroll
        for (int s = 0; s < 2; ++s)
#pragma unroll
            for (int j = 0; j < 4; ++j)
                acc[s][j] = __builtin_amdgcn_mfma_f32_16x16x32_bf16(
                    af[s], bfr[j], acc[s][j], 0, 0, 0);
    }

#pragma unroll
    for (int s = 0; s < 2; ++s) {
        const int row0 = m0 + wave * 32 + s * 16 + q * 4;
#pragma unroll
        for (int j = 0; j < 4; ++j) {
            const int col = n0 + j * 16 + r16;
            if (col < N) {
#pragma unroll
                for (int i = 0; i < 4; ++i)
                    C[(size_t)(row0 + i) * N + col] = acc[s][j][i];
            }
        }
    }
}

// ---------------------------------------------------------------------------
// fp32 -> bf16 straight cast
// ---------------------------------------------------------------------------
__global__ __launch_bounds__(256) void convert_bf16(
    const float* __restrict__ in, u16* __restrict__ out, int n)
{
    int i = blockIdx.x * 256 + threadIdx.x;
    if (i < n) out[i] = f2bf(in[i]);
}

// ---------------------------------------------------------------------------
// fp32[R,C] -> bf16[C,R] tiled transpose (for weight B^T layouts)
// ---------------------------------------------------------------------------
__global__ __launch_bounds__(256) void transpose_f32_bf16(
    const float* __restrict__ in, u16* __restrict__ out, int R, int C)
{
    __shared__ float t[32][33];
    const int tx = threadIdx.x, ty = threadIdx.y;
    const int c0 = blockIdx.x * 32, r0 = blockIdx.y * 32;
#pragma unroll
    for (int i = 0; i < 4; ++i) {
        int r = r0 + ty + i * 8, c = c0 + tx;
        if (r < R && c < C) t[ty + i * 8][tx] = in[(size_t)r * C + c];
    }
    __syncthreads();
#pragma unroll
    for (int i = 0; i < 4; ++i) {
        int oR = c0 + ty + i * 8, oC = r0 + tx;
        if (oR < C && oC < R) out[(size_t)oR * R + oC] = f2bf(t[tx][ty + i * 8]);
    }
}

// ---------------------------------------------------------------------------
// causal depthwise conv (D_CONV=4) + bias + silu; writes fp32 + bf16 copies
// ---------------------------------------------------------------------------
__global__ __launch_bounds__(256) void conv_silu_kernel(
    const float* __restrict__ xz, const float* __restrict__ cw,
    const float* __restrict__ cb, float* __restrict__ uc, u16* __restrict__ ucbf)
{
    const int idx = blockIdx.x * 256 + threadIdx.x;   // over B*L*DI
    const int d   = idx & (DI - 1);
    const int pos = idx >> 11;                        // b*L + l
    const int l   = pos & (L_SZ - 1);
    float s = cb[d];
#pragma unroll
    for (int k = 0; k < 4; ++k) {
        int ls = l + k - 3;
        if (ls >= 0)
            s = fmaf(xz[(size_t)(pos + k - 3) * (2 * DI) + d], cw[d * 4 + k], s);
    }
    float v = s / (1.f + __expf(-s));   // silu
    uc[idx]   = v;
    ucbf[idx] = f2bf(v);
}

// ---------------------------------------------------------------------------
// extract dt columns (x_dbl[:, :64]) as bf16 for the delta GEMM
// ---------------------------------------------------------------------------
__global__ __launch_bounds__(256) void extract_dt(
    const float* __restrict__ xdbl, u16* __restrict__ dtbf)
{
    int i = blockIdx.x * 256 + threadIdx.x;   // 2048*64
    int r = i >> 6, c = i & 63;
    dtbf[i] = f2bf(xdbl[(size_t)r * NXD + c]);
}

// ---------------------------------------------------------------------------
// delta = softplus(delta_pre + b_dt), in place
// ---------------------------------------------------------------------------
__global__ __launch_bounds__(256) void bias_softplus(
    float* __restrict__ dl, const float* __restrict__ bdt)
{
    int i = blockIdx.x * 256 + threadIdx.x;   // B*L*DI
    float v = dl[i] + bdt[i & (DI - 1)];
    dl[i] = (v > 20.f) ? v : log1pf(__expf(v));
}

// ---------------------------------------------------------------------------
// Selective scan, 3-pass chunked. Thread = one (b, d); h[16] in registers.
// Pass 1: per-chunk local scan from h=0; store h_loc[16], P=prod(dA)[16].
// Pass 2: serial stitch over 16 chunks; hbuf becomes h0 per chunk.
// Pass 3: replay with correct h0; y -> (y + u*D)*silu(z) -> bf16.
// ---------------------------------------------------------------------------
__global__ __launch_bounds__(256) void scan_pass1(
    const float* __restrict__ delta, const float* __restrict__ uc,
    const float* __restrict__ xdbl, const float* __restrict__ A_log,
    float* __restrict__ hbuf, float* __restrict__ pbuf)
{
    const int c = blockIdx.x;                       // chunk
    const int d = blockIdx.y * 256 + threadIdx.x;   // channel
    const int b = blockIdx.z;
    float Av[16], h[16], P[16];
#pragma unroll
    for (int n = 0; n < 16; ++n) {
        Av[n] = -__expf(A_log[d * 16 + n]);
        h[n] = 0.f; P[n] = 1.f;
    }
    const int rowbase = b * L_SZ + c * CL;
    for (int i = 0; i < CL; ++i) {
        const int row = rowbase + i;
        float dlt = delta[(size_t)row * DI + d];
        float uu  = uc[(size_t)row * DI + d];
        float du  = dlt * uu;
        const float* xr = xdbl + (size_t)row * NXD;   // wave-uniform address
#pragma unroll
        for (int n = 0; n < 16; ++n) {
            float e = __expf(dlt * Av[n]);
            P[n] *= e;
            h[n] = fmaf(e, h[n], du * xr[DTR + n]);
        }
    }
    size_t base = ((size_t)((b * NCHUNK + c) * DI + d)) * 16;
#pragma unroll
    for (int n = 0; n < 16; ++n) { hbuf[base + n] = h[n]; pbuf[base + n] = P[n]; }
}

__global__ __launch_bounds__(256) void scan_pass2(
    float* __restrict__ hbuf, const float* __restrict__ pbuf)
{
    const int d = blockIdx.x * 256 + threadIdx.x;
    const int b = blockIdx.y;
    float h0[16];
#pragma unroll
    for (int n = 0; n < 16; ++n) h0[n] = 0.f;
    for (int cc = 0; cc < NCHUNK; ++cc) {
        size_t base = ((size_t)((b * NCHUNK + cc) * DI + d)) * 16;
#pragma unroll
        for (int n = 0; n < 16; ++n) {
            float hl = hbuf[base + n];
            float Pl = pbuf[base + n];
            hbuf[base + n] = h0[n];                 // h0 entering chunk cc
            h0[n] = fmaf(Pl, h0[n], hl);
        }
    }
}

__global__ __launch_bounds__(256) void scan_pass3(
    const float* __restrict__ delta, const float* __restrict__ uc,
    const float* __restrict__ xdbl, const float* __restrict__ A_log,
    const float* __restrict__ hbuf, const float* __restrict__ xz,
    const float* __restrict__ Dskip, u16* __restrict__ ybf)
{
    const int c = blockIdx.x;
    const int d = blockIdx.y * 256 + threadIdx.x;
    const int b = blockIdx.z;
    float Av[16], h[16];
    size_t base = ((size_t)((b * NCHUNK + c) * DI + d)) * 16;
#pragma unroll
    for (int n = 0; n < 16; ++n) {
        Av[n] = -__expf(A_log[d * 16 + n]);
        h[n]  = hbuf[base + n];
    }
    const float Dk = Dskip[d];
    const int rowbase = b * L_SZ + c * CL;
    for (int i = 0; i < CL; ++i) {
        const int row = rowbase + i;
        float dlt = delta[(size_t)row * DI + d];
        float uu  = uc[(size_t)row * DI + d];
        float du  = dlt * uu;
        const float* xr = xdbl + (size_t)row * NXD;
        float y = 0.f;
#pragma unroll
        for (int n = 0; n < 16; ++n) {
            float e = __expf(dlt * Av[n]);
            h[n] = fmaf(e, h[n], du * xr[DTR + n]);
            y = fmaf(h[n], xr[DTR + DS + n], y);
        }
        float zz = xz[(size_t)row * (2 * DI) + DI + d];
        float yv = fmaf(uu, Dk, y) * (zz / (1.f + __expf(-zz)));
        ybf[(size_t)row * DI + d] = f2bf(yv);
    }
}

// ---------------------------------------------------------------------------
// workspace layout (element offsets)
// ---------------------------------------------------------------------------
constexpr size_t OFF_XZ      = 0;                          // 8,388,608 f
constexpr size_t OFF_UC      = OFF_XZ   + 8388608;         // 4,194,304 f
constexpr size_t OFF_DELTA   = OFF_UC   + 4194304;         // 4,194,304 f
constexpr size_t OFF_XDBL    = OFF_DELTA + 4194304;        //   196,608 f
constexpr size_t OFF_HBUF    = OFF_XDBL + 196608;          // 1,048,576 f
constexpr size_t OFF_PBUF    = OFF_HBUF + 1048576;         // 1,048,576 f
constexpr size_t OFF_F32_END = OFF_PBUF + 1048576;
// bf16 region (u16 offsets from end of fp32 region)
constexpr size_t SOFF_XBF   = 0;                  // 2,097,152
constexpr size_t SOFF_WINT  = SOFF_XBF   + 2097152;  // 4,194,304
constexpr size_t SOFF_UCBF  = SOFF_WINT  + 4194304;  // 4,194,304
constexpr size_t SOFF_WXT   = SOFF_UCBF  + 4194304;  //   196,608
constexpr size_t SOFF_DTBF  = SOFF_WXT   + 196608;   //   131,072
constexpr size_t SOFF_WDTT  = SOFF_DTBF  + 131072;   //   131,072
constexpr size_t SOFF_WOUTT = SOFF_WDTT  + 131072;   // 2,097,152
constexpr size_t SOFF_YBF   = SOFF_WOUTT + 2097152;  // 4,194,304

extern "C" void kernel_launch(void* const* d_in, const int* in_sizes, int n_in,
                              void* d_out, int out_size, void* d_ws, size_t ws_size,
                              hipStream_t stream)
{
    const float* x     = (const float*)d_in[0];
    const float* W_in  = (const float*)d_in[1];
    const float* cw    = (const float*)d_in[2];
    const float* cb    = (const float*)d_in[3];
    const float* W_x   = (const float*)d_in[4];
    const float* W_dt  = (const float*)d_in[5];
    const float* b_dt  = (const float*)d_in[6];
    const float* A_log = (const float*)d_in[7];
    const float* Dsk   = (const float*)d_in[8];
    const float* W_out = (const float*)d_in[9];
    float* out = (float*)d_out;

    float* wsf  = (float*)d_ws;
    float* xz   = wsf + OFF_XZ;
    float* uc   = wsf + OFF_UC;
    float* dlt  = wsf + OFF_DELTA;
    float* xdbl = wsf + OFF_XDBL;
    float* hbuf = wsf + OFF_HBUF;
    float* pbuf = wsf + OFF_PBUF;
    u16* sb    = (u16*)(wsf + OFF_F32_END);
    u16* xbf   = sb + SOFF_XBF;
    u16* winT  = sb + SOFF_WINT;
    u16* ucbf  = sb + SOFF_UCBF;
    u16* wxT   = sb + SOFF_WXT;
    u16* dtbf  = sb + SOFF_DTBF;
    u16* wdtT  = sb + SOFF_WDTT;
    u16* woutT = sb + SOFF_WOUTT;
    u16* ybf   = sb + SOFF_YBF;

    dim3 tb(32, 8);

    // 1) bf16 casts / weight transposes
    convert_bf16<<<(B_SZ * L_SZ * DM + 255) / 256, 256, 0, stream>>>(x, xbf, B_SZ * L_SZ * DM);
    transpose_f32_bf16<<<dim3(2 * DI / 32, DM / 32), tb, 0, stream>>>(W_in, winT, DM, 2 * DI);
    transpose_f32_bf16<<<dim3((NXD + 31) / 32, DI / 32), tb, 0, stream>>>(W_x, wxT, DI, NXD);
    transpose_f32_bf16<<<dim3(DI / 32, (DTR + 31) / 32), tb, 0, stream>>>(W_dt, wdtT, DTR, DI);
    transpose_f32_bf16<<<dim3(DM / 32, DI / 32), tb, 0, stream>>>(W_out, woutT, DI, DM);

    // 2) xz = x @ W_in   (M=2048, N=4096, K=1024)
    gemm_bt_bf16<<<dim3(4096 / 64, 2048 / 128), 256, 0, stream>>>(xbf, winT, xz, 2048, 4096, 1024);

    // 3) conv + silu
    conv_silu_kernel<<<(B_SZ * L_SZ * DI) / 256, 256, 0, stream>>>(xz, cw, cb, uc, ucbf);

    // 4) x_dbl = u @ W_x  (M=2048, N=96, K=2048)
    gemm_bt_bf16<<<dim3(2, 2048 / 128), 256, 0, stream>>>(ucbf, wxT, xdbl, 2048, NXD, 2048);

    // 5) delta = softplus(dt @ W_dt + b_dt)  (M=2048, N=2048, K=64)
    extract_dt<<<(B_SZ * L_SZ * DTR) / 256, 256, 0, stream>>>(xdbl, dtbf);
    gemm_bt_bf16<<<dim3(2048 / 64, 2048 / 128), 256, 0, stream>>>(dtbf, wdtT, dlt, 2048, 2048, 64);
    bias_softplus<<<(B_SZ * L_SZ * DI) / 256, 256, 0, stream>>>(dlt, b_dt);

    // 6) selective scan (3-pass chunked)
    scan_pass1<<<dim3(NCHUNK, DI / 256, B_SZ), 256, 0, stream>>>(dlt, uc, xdbl, A_log, hbuf, pbuf);
    scan_pass2<<<dim3(DI / 256, B_SZ), 256, 0, stream>>>(hbuf, pbuf);
    scan_pass3<<<dim3(NCHUNK, DI / 256, B_SZ), 256, 0, stream>>>(dlt, uc, xdbl, A_log, hbuf, xz, Dsk, ybf);

    // 7) out = y @ W_out  (M=2048, N=1024, K=2048)
    gemm_bt_bf16<<<dim3(1024 / 64, 2048 / 128), 256, 0, stream>>>(ybf, woutT, out, 2048, 1024, 2048);
}

// Round 2
// 331.091 us; speedup vs baseline: 1.0137x; 1.0137x over previous
//
#include <hip/hip_runtime.h>

// ---------------------------------------------------------------------------
// MambaBlock fused pipeline, MI355X (gfx950) — round 2
// B=2, L=1024, D_MODEL=1024, D_INNER=2048, D_STATE=16, D_CONV=4, DT_RANK=64
//
// Changes vs round 1:
//  * gemm128: m97-style 128x128x32 tile, global_load_lds(16B) staging,
//    16 MFMA : 8 ds_read_b128 per K-tile, optional fused bias+softplus
//    epilogue (used for delta GEMM -> removes bias_softplus kernel).
//  * x_dbl (N=96) GEMM: split-K x8 (grid 32 -> 256 blocks) + fused reduce
//    that also emits the bf16 dt matrix (removes extract_dt kernel).
// ---------------------------------------------------------------------------

typedef unsigned short u16;
typedef unsigned int   u32;

#define B_SZ 2
#define L_SZ 1024
#define DM   1024
#define DI   2048
#define DS   16
#define DTR  64
#define NXD  96      /* DTR + 2*DS */
#define NCHUNK 16
#define CL   64      /* chunk length: NCHUNK*CL = L */
#define KSPLIT 8
#define KC     256   /* 2048 / KSPLIT */

typedef __bf16 bf16x8 __attribute__((ext_vector_type(8)));
typedef float  f32x4  __attribute__((ext_vector_type(4)));

__device__ __forceinline__ u16 f2bf(float f) {
    u32 x = __float_as_uint(f);
    x += 0x7fffu + ((x >> 16) & 1u);   // round-to-nearest-even
    return (u16)(x >> 16);
}

__device__ __forceinline__ void gld_lds16(const u16* g, u16* l) {
    __builtin_amdgcn_global_load_lds(
        (const __attribute__((address_space(1))) u32*)g,
        (__attribute__((address_space(3))) u32*)l, 16, 0, 0);
}

// ---------------------------------------------------------------------------
// m97-style GEMM: C[M,N] = A[M,K] * BT[N,K]^T, fp32 out.
// 128x128 tile, BK=32, 256 threads = 4 waves, wave computes 64x64 (4x4 MFMAs).
// Requires M%128==0, N%128==0, K%32==0, K%8==0 (16B-aligned rows).
// op==1: out = softplus(acc + bias[col])
// ---------------------------------------------------------------------------
__global__ __launch_bounds__(256) void gemm128(
    const u16* __restrict__ A, const u16* __restrict__ BT,
    float* __restrict__ C, const float* __restrict__ bias,
    int M, int N, int K, int op)
{
    __shared__ u16 As[128 * 32];   // 8 KB, unpadded (global_load_lds layout)
    __shared__ u16 Bs[128 * 32];   // 8 KB

    const int tid  = threadIdx.x;
    const int wave = tid >> 6;
    const int lane = tid & 63;
    const int q    = lane >> 4;
    const int r16  = lane & 15;
    const int wm   = (wave & 1) * 64;
    const int wn   = (wave >> 1) * 64;
    const int m0   = blockIdx.y * 128;
    const int n0   = blockIdx.x * 128;
    const int srow = tid >> 2;          // 0..63
    const int sseg = (tid & 3) * 8;     // k-segment in shorts

    const u16* gA0 = A  + (size_t)(m0 + srow)      * K + sseg;
    const u16* gA1 = A  + (size_t)(m0 + 64 + srow) * K + sseg;
    const u16* gB0 = BT + (size_t)(n0 + srow)      * K + sseg;
    const u16* gB1 = BT + (size_t)(n0 + 64 + srow) * K + sseg;
    u16* lA0 = As + tid * 8;
    u16* lA1 = As + 2048 + tid * 8;
    u16* lB0 = Bs + tid * 8;
    u16* lB1 = Bs + 2048 + tid * 8;

    f32x4 acc[4][4];
#pragma unroll
    for (int s = 0; s < 4; ++s)
#pragma unroll
        for (int j = 0; j < 4; ++j) acc[s][j] = (f32x4){0.f, 0.f, 0.f, 0.f};

    for (int k0 = 0; k0 < K; k0 += 32) {
        __syncthreads();                       // LDS free (prev ds_reads done)
        gld_lds16(gA0 + k0, lA0);
        gld_lds16(gA1 + k0, lA1);
        gld_lds16(gB0 + k0, lB0);
        gld_lds16(gB1 + k0, lB1);
        __syncthreads();                       // drains vmcnt -> LDS valid

        bf16x8 af[4], bfr[4];
#pragma unroll
        for (int s = 0; s < 4; ++s)
            af[s] = *(const bf16x8*)(As + (wm + s * 16 + r16) * 32 + q * 8);
#pragma unroll
        for (int j = 0; j < 4; ++j)
            bfr[j] = *(const bf16x8*)(Bs + (wn + j * 16 + r16) * 32 + q * 8);
#pragma unroll
        for (int s = 0; s < 4; ++s)
#pragma unroll
            for (int j = 0; j < 4; ++j)
                acc[s][j] = __builtin_amdgcn_mfma_f32_16x16x32_bf16(
                    af[s], bfr[j], acc[s][j], 0, 0, 0);
    }

#pragma unroll
    for (int s = 0; s < 4; ++s) {
        const int row0 = m0 + wm + s * 16 + q * 4;
#pragma unroll
        for (int j = 0; j < 4; ++j) {
            const int col = n0 + wn + j * 16 + r16;
            if (op == 1) {
                const float bv = bias[col];
#pragma unroll
                for (int i = 0; i < 4; ++i) {
                    float v = acc[s][j][i] + bv;
                    v = (v > 20.f) ? v : log1pf(__expf(v));
                    C[(size_t)(row0 + i) * N + col] = v;
                }
            } else {
#pragma unroll
                for (int i = 0; i < 4; ++i)
                    C[(size_t)(row0 + i) * N + col] = acc[s][j][i];
            }
        }
    }
}

// ---------------------------------------------------------------------------
// Skinny-N split-K GEMM (for x_dbl, N=96): tile 128x64x32, register staging,
// blockIdx.z = K-chunk. Writes partial C per chunk.
// ---------------------------------------------------------------------------
__global__ __launch_bounds__(256) void gemm_skinny_splitk(
    const u16* __restrict__ A, const u16* __restrict__ BT,
    float* __restrict__ Cpart, int M, int N, int K)
{
    constexpr int LDT = 40;
    __shared__ u16 As[128 * LDT];
    __shared__ u16 Bs[64 * LDT];

    const int tid  = threadIdx.x;
    const int wave = tid >> 6;
    const int lane = tid & 63;
    const int q    = lane >> 4;
    const int r16  = lane & 15;
    const int m0   = blockIdx.y * 128;
    const int n0   = blockIdx.x * 64;
    const int kcs  = blockIdx.z * KC;
    const int sr   = tid >> 2;
    const int ss   = (tid & 3) * 8;

    f32x4 acc[2][4];
#pragma unroll
    for (int s = 0; s < 2; ++s)
#pragma unroll
        for (int j = 0; j < 4; ++j) acc[s][j] = (f32x4){0.f, 0.f, 0.f, 0.f};

    const int  bcol   = n0 + sr;
    const bool bvalid = bcol < N;

    for (int k0 = kcs; k0 < kcs + KC; k0 += 32) {
        __syncthreads();
        uint4 a0 = *(const uint4*)(A + (size_t)(m0 + sr)      * K + k0 + ss);
        uint4 a1 = *(const uint4*)(A + (size_t)(m0 + 64 + sr) * K + k0 + ss);
        uint4 bv = make_uint4(0u, 0u, 0u, 0u);
        if (bvalid) bv = *(const uint4*)(BT + (size_t)bcol * K + k0 + ss);
        *(uint4*)(As + sr * LDT + ss)        = a0;
        *(uint4*)(As + (64 + sr) * LDT + ss) = a1;
        *(uint4*)(Bs + sr * LDT + ss)        = bv;
        __syncthreads();

        bf16x8 af[2], bfr[4];
#pragma unroll
        for (int s = 0; s < 2; ++s)
            af[s] = *(const bf16x8*)(As + (wave * 32 + s * 16 + r16) * LDT + q * 8);
#pragma unroll
        for (int j = 0; j < 4; ++j)
            bfr[j] = *(const bf16x8*)(Bs + (j * 16 + r16) * LDT + q * 8);
#pragma unroll
        for (int s = 0; s < 2; ++s)
#pragma unroll
            for (int j = 0; j < 4; ++j)
                acc[s][j] = __builtin_amdgcn_mfma_f32_16x16x32_bf16(
                    af[s], bfr[j], acc[s][j], 0, 0, 0);
    }

    float* Cp = Cpart + (size_t)blockIdx.z * M * N;
#pragma unroll
    for (int s = 0; s < 2; ++s) {
        const int row0 = m0 + wave * 32 + s * 16 + q * 4;
#pragma unroll
        for (int j = 0; j < 4; ++j) {
            const int col = n0 + j * 16 + r16;
            if (col < N) {
#pragma unroll
                for (int i = 0; i < 4; ++i)
                    Cp[(size_t)(row0 + i) * N + col] = acc[s][j][i];
            }
        }
    }
}

// ---------------------------------------------------------------------------
// reduce split-K partials -> xdbl fp32; also emit dt (cols 0..63) as bf16
// ---------------------------------------------------------------------------
__global__ __launch_bounds__(256) void reduce_xdbl(
    const float* __restrict__ part, float* __restrict__ xdbl,
    u16* __restrict__ dtbf)
{
    const int i = blockIdx.x * 256 + threadIdx.x;   // over 2048*96
    const int row = i / NXD, col = i - row * NXD;
    float v = 0.f;
#pragma unroll
    for (int s = 0; s < KSPLIT; ++s)
        v += part[(size_t)s * (B_SZ * L_SZ * NXD) + i];
    xdbl[i] = v;
    if (col < DTR) dtbf[row * DTR + col] = f2bf(v);
}

// ---------------------------------------------------------------------------
// fp32 -> bf16 straight cast
// ---------------------------------------------------------------------------
__global__ __launch_bounds__(256) void convert_bf16(
    const float* __restrict__ in, u16* __restrict__ out, int n)
{
    int i = blockIdx.x * 256 + threadIdx.x;
    if (i < n) out[i] = f2bf(in[i]);
}

// ---------------------------------------------------------------------------
// fp32[R,C] -> bf16[C,R] tiled transpose (weights -> B^T layout)
// ---------------------------------------------------------------------------
__global__ __launch_bounds__(256) void transpose_f32_bf16(
    const float* __restrict__ in, u16* __restrict__ out, int R, int C)
{
    __shared__ float t[32][33];
    const int tx = threadIdx.x, ty = threadIdx.y;
    const int c0 = blockIdx.x * 32, r0 = blockIdx.y * 32;
#pragma unroll
    for (int i = 0; i < 4; ++i) {
        int r = r0 + ty + i * 8, c = c0 + tx;
        if (r < R && c < C) t[ty + i * 8][tx] = in[(size_t)r * C + c];
    }
    __syncthreads();
#pragma unroll
    for (int i = 0; i < 4; ++i) {
        int oR = c0 + ty + i * 8, oC = r0 + tx;
        if (oR < C && oC < R) out[(size_t)oR * R + oC] = f2bf(t[tx][ty + i * 8]);
    }
}

// ---------------------------------------------------------------------------
// causal depthwise conv (D_CONV=4) + bias + silu; writes fp32 + bf16 copies
// ---------------------------------------------------------------------------
__global__ __launch_bounds__(256) void conv_silu_kernel(
    const float* __restrict__ xz, const float* __restrict__ cw,
    const float* __restrict__ cb, float* __restrict__ uc, u16* __restrict__ ucbf)
{
    const int idx = blockIdx.x * 256 + threadIdx.x;   // over B*L*DI
    const int d   = idx & (DI - 1);
    const int pos = idx >> 11;                        // b*L + l
    const int l   = pos & (L_SZ - 1);
    float s = cb[d];
#pragma unroll
    for (int k = 0; k < 4; ++k) {
        int ls = l + k - 3;
        if (ls >= 0)
            s = fmaf(xz[(size_t)(pos + k - 3) * (2 * DI) + d], cw[d * 4 + k], s);
    }
    float v = s / (1.f + __expf(-s));   // silu
    uc[idx]   = v;
    ucbf[idx] = f2bf(v);
}

// ---------------------------------------------------------------------------
// Selective scan, 3-pass chunked (unchanged from round 1)
// ---------------------------------------------------------------------------
__global__ __launch_bounds__(256) void scan_pass1(
    const float* __restrict__ delta, const float* __restrict__ uc,
    const float* __restrict__ xdbl, const float* __restrict__ A_log,
    float* __restrict__ hbuf, float* __restrict__ pbuf)
{
    const int c = blockIdx.x;
    const int d = blockIdx.y * 256 + threadIdx.x;
    const int b = blockIdx.z;
    float Av[16], h[16], P[16];
#pragma unroll
    for (int n = 0; n < 16; ++n) {
        Av[n] = -__expf(A_log[d * 16 + n]);
        h[n] = 0.f; P[n] = 1.f;
    }
    const int rowbase = b * L_SZ + c * CL;
    for (int i = 0; i < CL; ++i) {
        const int row = rowbase + i;
        float dlt = delta[(size_t)row * DI + d];
        float uu  = uc[(size_t)row * DI + d];
        float du  = dlt * uu;
        const float* xr = xdbl + (size_t)row * NXD;   // block-uniform address
#pragma unroll
        for (int n = 0; n < 16; ++n) {
            float e = __expf(dlt * Av[n]);
            P[n] *= e;
            h[n] = fmaf(e, h[n], du * xr[DTR + n]);
        }
    }
    size_t base = ((size_t)((b * NCHUNK + c) * DI + d)) * 16;
#pragma unroll
    for (int n = 0; n < 16; ++n) { hbuf[base + n] = h[n]; pbuf[base + n] = P[n]; }
}

__global__ __launch_bounds__(256) void scan_pass2(
    float* __restrict__ hbuf, const float* __restrict__ pbuf)
{
    const int d = blockIdx.x * 256 + threadIdx.x;
    const int b = blockIdx.y;
    float h0[16];
#pragma unroll
    for (int n = 0; n < 16; ++n) h0[n] = 0.f;
    for (int cc = 0; cc < NCHUNK; ++cc) {
        size_t base = ((size_t)((b * NCHUNK + cc) * DI + d)) * 16;
#pragma unroll
        for (int n = 0; n < 16; ++n) {
            float hl = hbuf[base + n];
            float Pl = pbuf[base + n];
            hbuf[base + n] = h0[n];
            h0[n] = fmaf(Pl, h0[n], hl);
        }
    }
}

__global__ __launch_bounds__(256) void scan_pass3(
    const float* __restrict__ delta, const float* __restrict__ uc,
    const float* __restrict__ xdbl, const float* __restrict__ A_log,
    const float* __restrict__ hbuf, const float* __restrict__ xz,
    const float* __restrict__ Dskip, u16* __restrict__ ybf)
{
    const int c = blockIdx.x;
    const int d = blockIdx.y * 256 + threadIdx.x;
    const int b = blockIdx.z;
    float Av[16], h[16];
    size_t base = ((size_t)((b * NCHUNK + c) * DI + d)) * 16;
#pragma unroll
    for (int n = 0; n < 16; ++n) {
        Av[n] = -__expf(A_log[d * 16 + n]);
        h[n]  = hbuf[base + n];
    }
    const float Dk = Dskip[d];
    const int rowbase = b * L_SZ + c * CL;
    for (int i = 0; i < CL; ++i) {
        const int row = rowbase + i;
        float dlt = delta[(size_t)row * DI + d];
        float uu  = uc[(size_t)row * DI + d];
        float du  = dlt * uu;
        const float* xr = xdbl + (size_t)row * NXD;
        float y = 0.f;
#pragma unroll
        for (int n = 0; n < 16; ++n) {
            float e = __expf(dlt * Av[n]);
            h[n] = fmaf(e, h[n], du * xr[DTR + n]);
            y = fmaf(h[n], xr[DTR + DS + n], y);
        }
        float zz = xz[(size_t)row * (2 * DI) + DI + d];
        float yv = fmaf(uu, Dk, y) * (zz / (1.f + __expf(-zz)));
        ybf[(size_t)row * DI + d] = f2bf(yv);
    }
}

// ---------------------------------------------------------------------------
// workspace layout (element offsets)
// ---------------------------------------------------------------------------
constexpr size_t OFF_XZ      = 0;                          // 8,388,608 f
constexpr size_t OFF_UC      = OFF_XZ    + 8388608;        // 4,194,304 f
constexpr size_t OFF_DELTA   = OFF_UC    + 4194304;        // 4,194,304 f
constexpr size_t OFF_XDBL    = OFF_DELTA + 4194304;        //   196,608 f
constexpr size_t OFF_HBUF    = OFF_XDBL  + 196608;         // 1,048,576 f
constexpr size_t OFF_PBUF    = OFF_HBUF  + 1048576;        // 1,048,576 f
constexpr size_t OFF_XPART   = OFF_PBUF  + 1048576;        // 1,572,864 f
constexpr size_t OFF_F32_END = OFF_XPART + 1572864;
// bf16 region (u16 offsets from end of fp32 region)
constexpr size_t SOFF_XBF   = 0;                     // 2,097,152
constexpr size_t SOFF_WINT  = SOFF_XBF   + 2097152;  // 4,194,304
constexpr size_t SOFF_UCBF  = SOFF_WINT  + 4194304;  // 4,194,304
constexpr size_t SOFF_WXT   = SOFF_UCBF  + 4194304;  //   196,608
constexpr size_t SOFF_DTBF  = SOFF_WXT   + 196608;   //   131,072
constexpr size_t SOFF_WDTT  = SOFF_DTBF  + 131072;   //   131,072
constexpr size_t SOFF_WOUTT = SOFF_WDTT  + 131072;   // 2,097,152
constexpr size_t SOFF_YBF   = SOFF_WOUTT + 2097152;  // 4,194,304

extern "C" void kernel_launch(void* const* d_in, const int* in_sizes, int n_in,
                              void* d_out, int out_size, void* d_ws, size_t ws_size,
                              hipStream_t stream)
{
    const float* x     = (const float*)d_in[0];
    const float* W_in  = (const float*)d_in[1];
    const float* cw    = (const float*)d_in[2];
    const float* cb    = (const float*)d_in[3];
    const float* W_x   = (const float*)d_in[4];
    const float* W_dt  = (const float*)d_in[5];
    const float* b_dt  = (const float*)d_in[6];
    const float* A_log = (const float*)d_in[7];
    const float* Dsk   = (const float*)d_in[8];
    const float* W_out = (const float*)d_in[9];
    float* out = (float*)d_out;

    float* wsf   = (float*)d_ws;
    float* xz    = wsf + OFF_XZ;
    float* uc    = wsf + OFF_UC;
    float* dlt   = wsf + OFF_DELTA;
    float* xdbl  = wsf + OFF_XDBL;
    float* hbuf  = wsf + OFF_HBUF;
    float* pbuf  = wsf + OFF_PBUF;
    float* xpart = wsf + OFF_XPART;
    u16* sb    = (u16*)(wsf + OFF_F32_END);
    u16* xbf   = sb + SOFF_XBF;
    u16* winT  = sb + SOFF_WINT;
    u16* ucbf  = sb + SOFF_UCBF;
    u16* wxT   = sb + SOFF_WXT;
    u16* dtbf  = sb + SOFF_DTBF;
    u16* wdtT  = sb + SOFF_WDTT;
    u16* woutT = sb + SOFF_WOUTT;
    u16* ybf   = sb + SOFF_YBF;

    dim3 tb(32, 8);

    // 1) bf16 casts / weight transposes
    convert_bf16<<<(B_SZ * L_SZ * DM + 255) / 256, 256, 0, stream>>>(x, xbf, B_SZ * L_SZ * DM);
    transpose_f32_bf16<<<dim3(2 * DI / 32, DM / 32), tb, 0, stream>>>(W_in, winT, DM, 2 * DI);
    transpose_f32_bf16<<<dim3((NXD + 31) / 32, DI / 32), tb, 0, stream>>>(W_x, wxT, DI, NXD);
    transpose_f32_bf16<<<dim3(DI / 32, (DTR + 31) / 32), tb, 0, stream>>>(W_dt, wdtT, DTR, DI);
    transpose_f32_bf16<<<dim3(DM / 32, DI / 32), tb, 0, stream>>>(W_out, woutT, DI, DM);

    // 2) xz = x @ W_in   (M=2048, N=4096, K=1024)
    gemm128<<<dim3(4096 / 128, 2048 / 128), 256, 0, stream>>>(
        xbf, winT, xz, nullptr, 2048, 4096, 1024, 0);

    // 3) conv + silu
    conv_silu_kernel<<<(B_SZ * L_SZ * DI) / 256, 256, 0, stream>>>(xz, cw, cb, uc, ucbf);

    // 4) x_dbl = u @ W_x  (M=2048, N=96, K=2048) — split-K x8 + reduce
    gemm_skinny_splitk<<<dim3(2, 2048 / 128, KSPLIT), 256, 0, stream>>>(
        ucbf, wxT, xpart, 2048, NXD, 2048);
    reduce_xdbl<<<(B_SZ * L_SZ * NXD) / 256, 256, 0, stream>>>(xpart, xdbl, dtbf);

    // 5) delta = softplus(dt @ W_dt + b_dt)  (M=2048, N=2048, K=64) — fused epilogue
    gemm128<<<dim3(2048 / 128, 2048 / 128), 256, 0, stream>>>(
        dtbf, wdtT, dlt, b_dt, 2048, 2048, 64, 1);

    // 6) selective scan (3-pass chunked)
    scan_pass1<<<dim3(NCHUNK, DI / 256, B_SZ), 256, 0, stream>>>(dlt, uc, xdbl, A_log, hbuf, pbuf);
    scan_pass2<<<dim3(DI / 256, B_SZ), 256, 0, stream>>>(hbuf, pbuf);
    scan_pass3<<<dim3(NCHUNK, DI / 256, B_SZ), 256, 0, stream>>>(dlt, uc, xdbl, A_log, hbuf, xz, Dsk, ybf);

    // 7) out = y @ W_out  (M=2048, N=1024, K=2048)
    gemm128<<<dim3(1024 / 128, 2048 / 128), 256, 0, stream>>>(
        ybf, woutT, out, nullptr, 2048, 1024, 2048, 0);
}

// Round 3
// 278.776 us; speedup vs baseline: 1.2039x; 1.1877x over previous
//
#include <hip/hip_runtime.h>

// ---------------------------------------------------------------------------
// MambaBlock fused pipeline, MI355X (gfx950) — round 3
// B=2, L=1024, D_MODEL=1024, D_INNER=2048, D_STATE=16, D_CONV=4, DT_RANK=64
//
// Changes vs round 2 (theory: GEMM-out + scan_pass2 were latency-bound):
//  * gemm128u2: BK=64 as two BK=32 stages (4 LDS bufs, one barrier pair per
//    64-K) -> half the barrier/latency events; optional split-K via gridDim.z.
//  * GEMM-out: split-K x4 (128 -> 512 blocks, 2/CU) + float4 reduce kernel.
//    Partials live in the dead xz region (exact size match).
//  * scan_pass2: re-parallelized over (b,d,n): 16 -> 256 blocks, coalesced.
//  * prep: 5 cast/transpose launches fused into 1 kernel.
// ---------------------------------------------------------------------------

typedef unsigned short u16;
typedef unsigned int   u32;

#define B_SZ 2
#define L_SZ 1024
#define DM   1024
#define DI   2048
#define DS   16
#define DTR  64
#define NXD  96      /* DTR + 2*DS */
#define NCHUNK 16
#define CL   64      /* chunk length: NCHUNK*CL = L */
#define KSPLIT 8     /* split-K for skinny x_dbl GEMM */
#define KC     256   /* 2048 / KSPLIT */
#define OSPLIT 4     /* split-K for GEMM-out */

typedef __bf16 bf16x8 __attribute__((ext_vector_type(8)));
typedef float  f32x4  __attribute__((ext_vector_type(4)));

__device__ __forceinline__ u16 f2bf(float f) {
    u32 x = __float_as_uint(f);
    x += 0x7fffu + ((x >> 16) & 1u);   // round-to-nearest-even
    return (u16)(x >> 16);
}

__device__ __forceinline__ void gld_lds16(const u16* g, u16* l) {
    __builtin_amdgcn_global_load_lds(
        (const __attribute__((address_space(1))) u32*)g,
        (__attribute__((address_space(3))) u32*)l, 16, 0, 0);
}

// ---------------------------------------------------------------------------
// m97-style GEMM, BK=64 via two BK=32 stages: C = A[M,K] * BT[N,K]^T.
// 128x128 tile, 256 thr = 4 waves (2x2), wave computes 64x64 (4x4 MFMA x2).
// gridDim.z = split-K chunks; KCHUNK = K / gridDim.z, KCHUNK % 64 == 0.
// op==1: out = softplus(acc + bias[col]).
// ---------------------------------------------------------------------------
__global__ __launch_bounds__(256) void gemm128u2(
    const u16* __restrict__ A, const u16* __restrict__ BT,
    float* __restrict__ C, const float* __restrict__ bias,
    int M, int N, int K, int KCHUNK, int op)
{
    __shared__ u16 As0[128 * 32];
    __shared__ u16 Bs0[128 * 32];
    __shared__ u16 As1[128 * 32];
    __shared__ u16 Bs1[128 * 32];

    const int tid  = threadIdx.x;
    const int wave = tid >> 6;
    const int lane = tid & 63;
    const int q    = lane >> 4;
    const int r16  = lane & 15;
    const int wm   = (wave & 1) * 64;
    const int wn   = (wave >> 1) * 64;
    const int m0   = blockIdx.y * 128;
    const int n0   = blockIdx.x * 128;
    const int srow = tid >> 2;          // 0..63
    const int sseg = (tid & 3) * 8;     // k-segment (shorts)
    const int kb   = blockIdx.z * KCHUNK;

    const u16* gA0 = A  + (size_t)(m0 + srow)      * K + sseg;
    const u16* gA1 = A  + (size_t)(m0 + 64 + srow) * K + sseg;
    const u16* gB0 = BT + (size_t)(n0 + srow)      * K + sseg;
    const u16* gB1 = BT + (size_t)(n0 + 64 + srow) * K + sseg;
    u16* lA0 = As0 + tid * 8;  u16* lA0b = As0 + 2048 + tid * 8;
    u16* lB0 = Bs0 + tid * 8;  u16* lB0b = Bs0 + 2048 + tid * 8;
    u16* lA1 = As1 + tid * 8;  u16* lA1b = As1 + 2048 + tid * 8;
    u16* lB1 = Bs1 + tid * 8;  u16* lB1b = Bs1 + 2048 + tid * 8;

    f32x4 acc[4][4];
#pragma unroll
    for (int s = 0; s < 4; ++s)
#pragma unroll
        for (int j = 0; j < 4; ++j) acc[s][j] = (f32x4){0.f, 0.f, 0.f, 0.f};

    for (int k0 = kb; k0 < kb + KCHUNK; k0 += 64) {
        __syncthreads();                 // prev ds_reads done, LDS reusable
        gld_lds16(gA0 + k0, lA0);
        gld_lds16(gA1 + k0, lA0b);
        gld_lds16(gB0 + k0, lB0);
        gld_lds16(gB1 + k0, lB0b);
        gld_lds16(gA0 + k0 + 32, lA1);
        gld_lds16(gA1 + k0 + 32, lA1b);
        gld_lds16(gB0 + k0 + 32, lB1);
        gld_lds16(gB1 + k0 + 32, lB1b);
        __syncthreads();                 // drains vmcnt -> both stages valid

        bf16x8 af[4], bfr[4];
#pragma unroll
        for (int s = 0; s < 4; ++s)
            af[s] = *(const bf16x8*)(As0 + (wm + s * 16 + r16) * 32 + q * 8);
#pragma unroll
        for (int j = 0; j < 4; ++j)
            bfr[j] = *(const bf16x8*)(Bs0 + (wn + j * 16 + r16) * 32 + q * 8);
#pragma unroll
        for (int s = 0; s < 4; ++s)
#pragma unroll
            for (int j = 0; j < 4; ++j)
                acc[s][j] = __builtin_amdgcn_mfma_f32_16x16x32_bf16(
                    af[s], bfr[j], acc[s][j], 0, 0, 0);
#pragma unroll
        for (int s = 0; s < 4; ++s)
            af[s] = *(const bf16x8*)(As1 + (wm + s * 16 + r16) * 32 + q * 8);
#pragma unroll
        for (int j = 0; j < 4; ++j)
            bfr[j] = *(const bf16x8*)(Bs1 + (wn + j * 16 + r16) * 32 + q * 8);
#pragma unroll
        for (int s = 0; s < 4; ++s)
#pragma unroll
            for (int j = 0; j < 4; ++j)
                acc[s][j] = __builtin_amdgcn_mfma_f32_16x16x32_bf16(
                    af[s], bfr[j], acc[s][j], 0, 0, 0);
    }

    float* Cz = C + (size_t)blockIdx.z * M * N;
#pragma unroll
    for (int s = 0; s < 4; ++s) {
        const int row0 = m0 + wm + s * 16 + q * 4;
#pragma unroll
        for (int j = 0; j < 4; ++j) {
            const int col = n0 + wn + j * 16 + r16;
            if (op == 1) {
                const float bv = bias[col];
#pragma unroll
                for (int i = 0; i < 4; ++i) {
                    float v = acc[s][j][i] + bv;
                    v = (v > 20.f) ? v : log1pf(__expf(v));
                    Cz[(size_t)(row0 + i) * N + col] = v;
                }
            } else {
#pragma unroll
                for (int i = 0; i < 4; ++i)
                    Cz[(size_t)(row0 + i) * N + col] = acc[s][j][i];
            }
        }
    }
}

// ---------------------------------------------------------------------------
// reduce GEMM-out split-K partials (4 planes of M*N) -> final out, float4
// ---------------------------------------------------------------------------
__global__ __launch_bounds__(256) void reduce_out(
    const float* __restrict__ part, float* __restrict__ out, int n)
{
    const int i = (blockIdx.x * 256 + threadIdx.x) * 4;
    if (i >= n) return;
    f32x4 v = *(const f32x4*)(part + i);
#pragma unroll
    for (int s = 1; s < OSPLIT; ++s) {
        f32x4 p = *(const f32x4*)(part + (size_t)s * n + i);
        v.x += p.x; v.y += p.y; v.z += p.z; v.w += p.w;
    }
    *(f32x4*)(out + i) = v;
}

// ---------------------------------------------------------------------------
// Skinny-N split-K GEMM (x_dbl, N=96): 128x64x32 tile, register staging,
// blockIdx.z = K-chunk. Writes partial C per chunk.
// ---------------------------------------------------------------------------
__global__ __launch_bounds__(256) void gemm_skinny_splitk(
    const u16* __restrict__ A, const u16* __restrict__ BT,
    float* __restrict__ Cpart, int M, int N, int K)
{
    constexpr int LDT = 40;
    __shared__ u16 As[128 * LDT];
    __shared__ u16 Bs[64 * LDT];

    const int tid  = threadIdx.x;
    const int wave = tid >> 6;
    const int lane = tid & 63;
    const int q    = lane >> 4;
    const int r16  = lane & 15;
    const int m0   = blockIdx.y * 128;
    const int n0   = blockIdx.x * 64;
    const int kcs  = blockIdx.z * KC;
    const int sr   = tid >> 2;
    const int ss   = (tid & 3) * 8;

    f32x4 acc[2][4];
#pragma unroll
    for (int s = 0; s < 2; ++s)
#pragma unroll
        for (int j = 0; j < 4; ++j) acc[s][j] = (f32x4){0.f, 0.f, 0.f, 0.f};

    const int  bcol   = n0 + sr;
    const bool bvalid = bcol < N;

    for (int k0 = kcs; k0 < kcs + KC; k0 += 32) {
        __syncthreads();
        uint4 a0 = *(const uint4*)(A + (size_t)(m0 + sr)      * K + k0 + ss);
        uint4 a1 = *(const uint4*)(A + (size_t)(m0 + 64 + sr) * K + k0 + ss);
        uint4 bv = make_uint4(0u, 0u, 0u, 0u);
        if (bvalid) bv = *(const uint4*)(BT + (size_t)bcol * K + k0 + ss);
        *(uint4*)(As + sr * LDT + ss)        = a0;
        *(uint4*)(As + (64 + sr) * LDT + ss) = a1;
        *(uint4*)(Bs + sr * LDT + ss)        = bv;
        __syncthreads();

        bf16x8 af[2], bfr[4];
#pragma unroll
        for (int s = 0; s < 2; ++s)
            af[s] = *(const bf16x8*)(As + (wave * 32 + s * 16 + r16) * LDT + q * 8);
#pragma unroll
        for (int j = 0; j < 4; ++j)
            bfr[j] = *(const bf16x8*)(Bs + (j * 16 + r16) * LDT + q * 8);
#pragma unroll
        for (int s = 0; s < 2; ++s)
#pragma unroll
            for (int j = 0; j < 4; ++j)
                acc[s][j] = __builtin_amdgcn_mfma_f32_16x16x32_bf16(
                    af[s], bfr[j], acc[s][j], 0, 0, 0);
    }

    float* Cp = Cpart + (size_t)blockIdx.z * M * N;
#pragma unroll
    for (int s = 0; s < 2; ++s) {
        const int row0 = m0 + wave * 32 + s * 16 + q * 4;
#pragma unroll
        for (int j = 0; j < 4; ++j) {
            const int col = n0 + j * 16 + r16;
            if (col < N) {
#pragma unroll
                for (int i = 0; i < 4; ++i)
                    Cp[(size_t)(row0 + i) * N + col] = acc[s][j][i];
            }
        }
    }
}

// ---------------------------------------------------------------------------
// reduce split-K partials -> xdbl fp32; also emit dt (cols 0..63) as bf16
// ---------------------------------------------------------------------------
__global__ __launch_bounds__(256) void reduce_xdbl(
    const float* __restrict__ part, float* __restrict__ xdbl,
    u16* __restrict__ dtbf)
{
    const int i = blockIdx.x * 256 + threadIdx.x;   // over 2048*96
    const int row = i / NXD, col = i - row * NXD;
    float v = 0.f;
#pragma unroll
    for (int s = 0; s < KSPLIT; ++s)
        v += part[(size_t)s * (B_SZ * L_SZ * NXD) + i];
    xdbl[i] = v;
    if (col < DTR) dtbf[row * DTR + col] = f2bf(v);
}

// ---------------------------------------------------------------------------
// fused prep: x -> bf16 cast + 4 weight transposes (f32[R,C] -> bf16[C,R])
// block-uniform branch on blockIdx.x; 256 threads.
// ---------------------------------------------------------------------------
__device__ __forceinline__ void tr_tile(
    const float* __restrict__ in, u16* __restrict__ out,
    int R, int C, int tr, int tc, int tid, float (*t)[33])
{
    const int tx = tid & 31, ty = tid >> 5;
    const int r0 = tr * 32, c0 = tc * 32;
#pragma unroll
    for (int i = 0; i < 4; ++i) {
        int r = r0 + ty + i * 8, c = c0 + tx;
        if (r < R && c < C) t[ty + i * 8][tx] = in[(size_t)r * C + c];
    }
    __syncthreads();
#pragma unroll
    for (int i = 0; i < 4; ++i) {
        int oR = c0 + ty + i * 8, oC = r0 + tx;
        if (oR < C && oC < R) out[(size_t)oR * R + oC] = f2bf(t[tx][ty + i * 8]);
    }
}

__global__ __launch_bounds__(256) void prep_kernel(
    const float* __restrict__ x,     u16* __restrict__ xbf,
    const float* __restrict__ W_in,  u16* __restrict__ winT,
    const float* __restrict__ W_out, u16* __restrict__ woutT,
    const float* __restrict__ W_x,   u16* __restrict__ wxT,
    const float* __restrict__ W_dt,  u16* __restrict__ wdtT)
{
    __shared__ float t[32][33];
    const int id  = blockIdx.x;
    const int tid = threadIdx.x;
    if (id < 4096) {                                   // W_in: 1024x4096
        tr_tile(W_in, winT, 1024, 4096, id >> 7, id & 127, tid, t);
    } else if (id < 6144) {                            // W_out: 2048x1024
        int i2 = id - 4096;
        tr_tile(W_out, woutT, 2048, 1024, i2 >> 5, i2 & 31, tid, t);
    } else if (id < 6336) {                            // W_x: 2048x96
        int i3 = id - 6144;
        tr_tile(W_x, wxT, 2048, 96, i3 / 3, i3 % 3, tid, t);
    } else if (id < 6464) {                            // W_dt: 64x2048
        int i4 = id - 6336;
        tr_tile(W_dt, wdtT, 64, 2048, i4 >> 6, i4 & 63, tid, t);
    } else {                                           // x cast: 2,097,152
        int i = (id - 6464) * 256 + tid;
        xbf[i] = f2bf(x[i]);
    }
}

// ---------------------------------------------------------------------------
// causal depthwise conv (D_CONV=4) + bias + silu; writes fp32 + bf16 copies
// ---------------------------------------------------------------------------
__global__ __launch_bounds__(256) void conv_silu_kernel(
    const float* __restrict__ xz, const float* __restrict__ cw,
    const float* __restrict__ cb, float* __restrict__ uc, u16* __restrict__ ucbf)
{
    const int idx = blockIdx.x * 256 + threadIdx.x;   // over B*L*DI
    const int d   = idx & (DI - 1);
    const int pos = idx >> 11;                        // b*L + l
    const int l   = pos & (L_SZ - 1);
    float s = cb[d];
#pragma unroll
    for (int k = 0; k < 4; ++k) {
        int ls = l + k - 3;
        if (ls >= 0)
            s = fmaf(xz[(size_t)(pos + k - 3) * (2 * DI) + d], cw[d * 4 + k], s);
    }
    float v = s / (1.f + __expf(-s));   // silu
    uc[idx]   = v;
    ucbf[idx] = f2bf(v);
}

// ---------------------------------------------------------------------------
// Selective scan, 3-pass chunked.
// ---------------------------------------------------------------------------
__global__ __launch_bounds__(256) void scan_pass1(
    const float* __restrict__ delta, const float* __restrict__ uc,
    const float* __restrict__ xdbl, const float* __restrict__ A_log,
    float* __restrict__ hbuf, float* __restrict__ pbuf)
{
    const int c = blockIdx.x;
    const int d = blockIdx.y * 256 + threadIdx.x;
    const int b = blockIdx.z;
    float Av[16], h[16], P[16];
#pragma unroll
    for (int n = 0; n < 16; ++n) {
        Av[n] = -__expf(A_log[d * 16 + n]);
        h[n] = 0.f; P[n] = 1.f;
    }
    const int rowbase = b * L_SZ + c * CL;
    for (int i = 0; i < CL; ++i) {
        const int row = rowbase + i;
        float dlt = delta[(size_t)row * DI + d];
        float uu  = uc[(size_t)row * DI + d];
        float du  = dlt * uu;
        const float* xr = xdbl + (size_t)row * NXD;   // block-uniform address
#pragma unroll
        for (int n = 0; n < 16; ++n) {
            float e = __expf(dlt * Av[n]);
            P[n] *= e;
            h[n] = fmaf(e, h[n], du * xr[DTR + n]);
        }
    }
    size_t base = ((size_t)((b * NCHUNK + c) * DI + d)) * 16;
#pragma unroll
    for (int n = 0; n < 16; ++n) { hbuf[base + n] = h[n]; pbuf[base + n] = P[n]; }
}

// parallel over (b, d*16+n): coalesced, 256 blocks
__global__ __launch_bounds__(256) void scan_pass2(
    float* __restrict__ hbuf, const float* __restrict__ pbuf)
{
    const int j = blockIdx.x * 256 + threadIdx.x;   // d*16+n in [0, 32768)
    const int b = blockIdx.y;
    float h0 = 0.f;
    for (int cc = 0; cc < NCHUNK; ++cc) {
        size_t o = ((size_t)(b * NCHUNK + cc)) * (DI * 16) + j;
        float hl = hbuf[o];
        float Pl = pbuf[o];
        hbuf[o] = h0;                  // h0 entering chunk cc
        h0 = fmaf(Pl, h0, hl);
    }
}

__global__ __launch_bounds__(256) void scan_pass3(
    const float* __restrict__ delta, const float* __restrict__ uc,
    const float* __restrict__ xdbl, const float* __restrict__ A_log,
    const float* __restrict__ hbuf, const float* __restrict__ xz,
    const float* __restrict__ Dskip, u16* __restrict__ ybf)
{
    const int c = blockIdx.x;
    const int d = blockIdx.y * 256 + threadIdx.x;
    const int b = blockIdx.z;
    float Av[16], h[16];
    size_t base = ((size_t)((b * NCHUNK + c) * DI + d)) * 16;
#pragma unroll
    for (int n = 0; n < 16; ++n) {
        Av[n] = -__expf(A_log[d * 16 + n]);
        h[n]  = hbuf[base + n];
    }
    const float Dk = Dskip[d];
    const int rowbase = b * L_SZ + c * CL;
    for (int i = 0; i < CL; ++i) {
        const int row = rowbase + i;
        float dlt = delta[(size_t)row * DI + d];
        float uu  = uc[(size_t)row * DI + d];
        float du  = dlt * uu;
        const float* xr = xdbl + (size_t)row * NXD;
        float y = 0.f;
#pragma unroll
        for (int n = 0; n < 16; ++n) {
            float e = __expf(dlt * Av[n]);
            h[n] = fmaf(e, h[n], du * xr[DTR + n]);
            y = fmaf(h[n], xr[DTR + DS + n], y);
        }
        float zz = xz[(size_t)row * (2 * DI) + DI + d];
        float yv = fmaf(uu, Dk, y) * (zz / (1.f + __expf(-zz)));
        ybf[(size_t)row * DI + d] = f2bf(yv);
    }
}

// ---------------------------------------------------------------------------
// workspace layout (f32 element offsets). Temporal overlays:
//   - OFF_XZ region is reused for GEMM-out split-K partials (xz dead by then)
//   - OFF_SCRATCH holds xpart (phase 4), then hbuf+pbuf (phase 6)
// ---------------------------------------------------------------------------
constexpr size_t OFF_XZ      = 0;                          // 8,388,608 f (also 4x out-partials)
constexpr size_t OFF_UC      = OFF_XZ    + 8388608;        // 4,194,304 f
constexpr size_t OFF_DELTA   = OFF_UC    + 4194304;        // 4,194,304 f
constexpr size_t OFF_XDBL    = OFF_DELTA + 4194304;        //   196,608 f
constexpr size_t OFF_SCRATCH = OFF_XDBL  + 196608;         // 4,194,304 f
constexpr size_t OFF_F32_END = OFF_SCRATCH + 4194304;
// bf16 region (u16 offsets from end of fp32 region)
constexpr size_t SOFF_XBF   = 0;                     // 2,097,152
constexpr size_t SOFF_WINT  = SOFF_XBF   + 2097152;  // 4,194,304
constexpr size_t SOFF_UCBF  = SOFF_WINT  + 4194304;  // 4,194,304
constexpr size_t SOFF_WXT   = SOFF_UCBF  + 4194304;  //   196,608
constexpr size_t SOFF_DTBF  = SOFF_WXT   + 196608;   //   131,072
constexpr size_t SOFF_WDTT  = SOFF_DTBF  + 131072;   //   131,072
constexpr size_t SOFF_WOUTT = SOFF_WDTT  + 131072;   // 2,097,152
constexpr size_t SOFF_YBF   = SOFF_WOUTT + 2097152;  // 4,194,304

extern "C" void kernel_launch(void* const* d_in, const int* in_sizes, int n_in,
                              void* d_out, int out_size, void* d_ws, size_t ws_size,
                              hipStream_t stream)
{
    const float* x     = (const float*)d_in[0];
    const float* W_in  = (const float*)d_in[1];
    const float* cw    = (const float*)d_in[2];
    const float* cb    = (const float*)d_in[3];
    const float* W_x   = (const float*)d_in[4];
    const float* W_dt  = (const float*)d_in[5];
    const float* b_dt  = (const float*)d_in[6];
    const float* A_log = (const float*)d_in[7];
    const float* Dsk   = (const float*)d_in[8];
    const float* W_out = (const float*)d_in[9];
    float* out = (float*)d_out;

    float* wsf   = (float*)d_ws;
    float* xz    = wsf + OFF_XZ;
    float* opart = wsf + OFF_XZ;            // overlay: out split-K partials
    float* uc    = wsf + OFF_UC;
    float* dlt   = wsf + OFF_DELTA;
    float* xdbl  = wsf + OFF_XDBL;
    float* xpart = wsf + OFF_SCRATCH;       // overlay: x_dbl split-K partials
    float* hbuf  = wsf + OFF_SCRATCH;       // overlay: scan chunk states
    float* pbuf  = wsf + OFF_SCRATCH + 2097152;
    u16* sb    = (u16*)(wsf + OFF_F32_END);
    u16* xbf   = sb + SOFF_XBF;
    u16* winT  = sb + SOFF_WINT;
    u16* ucbf  = sb + SOFF_UCBF;
    u16* wxT   = sb + SOFF_WXT;
    u16* dtbf  = sb + SOFF_DTBF;
    u16* wdtT  = sb + SOFF_WDTT;
    u16* woutT = sb + SOFF_WOUTT;
    u16* ybf   = sb + SOFF_YBF;

    // 1) fused prep: x cast + 4 weight transposes (1 launch, 14656 blocks)
    prep_kernel<<<14656, 256, 0, stream>>>(x, xbf, W_in, winT, W_out, woutT,
                                           W_x, wxT, W_dt, wdtT);

    // 2) xz = x @ W_in   (M=2048, N=4096, K=1024), 512 blocks
    gemm128u2<<<dim3(4096 / 128, 2048 / 128, 1), 256, 0, stream>>>(
        xbf, winT, xz, nullptr, 2048, 4096, 1024, 1024, 0);

    // 3) conv + silu
    conv_silu_kernel<<<(B_SZ * L_SZ * DI) / 256, 256, 0, stream>>>(xz, cw, cb, uc, ucbf);

    // 4) x_dbl = u @ W_x  (M=2048, N=96, K=2048) — split-K x8 + reduce
    gemm_skinny_splitk<<<dim3(2, 2048 / 128, KSPLIT), 256, 0, stream>>>(
        ucbf, wxT, xpart, 2048, NXD, 2048);
    reduce_xdbl<<<(B_SZ * L_SZ * NXD) / 256, 256, 0, stream>>>(xpart, xdbl, dtbf);

    // 5) delta = softplus(dt @ W_dt + b_dt)  (M=2048, N=2048, K=64), fused epi
    gemm128u2<<<dim3(2048 / 128, 2048 / 128, 1), 256, 0, stream>>>(
        dtbf, wdtT, dlt, b_dt, 2048, 2048, 64, 64, 1);

    // 6) selective scan (3-pass chunked; pass2 coalesced over (b,d,n))
    scan_pass1<<<dim3(NCHUNK, DI / 256, B_SZ), 256, 0, stream>>>(dlt, uc, xdbl, A_log, hbuf, pbuf);
    scan_pass2<<<dim3(DI * 16 / 256, B_SZ), 256, 0, stream>>>(hbuf, pbuf);
    scan_pass3<<<dim3(NCHUNK, DI / 256, B_SZ), 256, 0, stream>>>(dlt, uc, xdbl, A_log, hbuf, xz, Dsk, ybf);

    // 7) out = y @ W_out  (M=2048, N=1024, K=2048) — split-K x4 + reduce
    //    partials overlay the (now dead) xz region
    gemm128u2<<<dim3(1024 / 128, 2048 / 128, OSPLIT), 256, 0, stream>>>(
        ybf, woutT, opart, nullptr, 2048, 1024, 2048, 2048 / OSPLIT, 0);
    reduce_out<<<(2048 * 1024 / 4 + 255) / 256, 256, 0, stream>>>(
        opart, out, 2048 * 1024);
}